// Round 7
// baseline (135.948 us; speedup 1.0000x reference)
//
#include <hip/hip_runtime.h>

// ModConv: y[b,o,p] = d[b,o] * sum_{c,tap} weight[o,c,tap] * style[b,c] * x[b,c,p+tap]
// Prologue (style, W2+wbf fused, d, border-zero, xspad) + bf16 MFMA implicit-GEMM conv.
// Conv: A (weights) direct global->VGPR (L1-served, LDS-free); B (pixels) via
// swizzled gload_lds 3-buffer pipeline; ONE raw s_barrier per K-tile; compiler
// counted vmcnt/lgkm waits do all ordering (T1+T2+T4+T5).

typedef __attribute__((ext_vector_type(8))) short bfx8;
typedef __attribute__((ext_vector_type(4))) float f32x4;
typedef __attribute__((ext_vector_type(4))) unsigned short us4;
typedef __attribute__((ext_vector_type(8))) unsigned short us8;

__device__ __forceinline__ unsigned short f2bf(float f) {
    unsigned int u = __builtin_bit_cast(unsigned int, f);
    u += 0x7FFFu + ((u >> 16) & 1u);          // round-to-nearest-even
    return (unsigned short)(u >> 16);
}

__device__ __forceinline__ void gload_lds16(const void* g, void* l) {
    __builtin_amdgcn_global_load_lds(
        (const __attribute__((address_space(1))) unsigned int*)g,
        (__attribute__((address_space(3))) unsigned int*)l,
        16, 0, 0);
}

__device__ __forceinline__ float wave_sum(float v) {
    #pragma unroll
    for (int m = 1; m < 64; m <<= 1) v += __shfl_xor(v, m, 64);
    return v;
}

__device__ __forceinline__ int shift_of(int t) {
    const int tap = t >> 3, q = t & 7;
    const int ky = tap / 3, kx = tap - ky * 3;
    return (ky * 34 + kx) * 512 + q * 64;
}

// ---------- prologue ----------

// style[b][c] = dot(w[b,:], affine_w[c,:]) + affine_b[c]; wave-per-output (8192 waves)
__global__ void style_kernel(const float* __restrict__ w,
                             const float* __restrict__ affine_w,
                             const float* __restrict__ affine_b,
                             float* __restrict__ style) {
    const int out = blockIdx.x * 4 + (threadIdx.x >> 6);
    const int lane = threadIdx.x & 63;
    const int b = out >> 9, c = out & 511;
    const float4 a0 = *(const float4*)(affine_w + (size_t)c * 512 + lane * 8);
    const float4 a1 = *(const float4*)(affine_w + (size_t)c * 512 + lane * 8 + 4);
    const float4 w0 = *(const float4*)(w + (size_t)b * 512 + lane * 8);
    const float4 w1 = *(const float4*)(w + (size_t)b * 512 + lane * 8 + 4);
    float acc = a0.x * w0.x + a0.y * w0.y + a0.z * w0.z + a0.w * w0.w
              + a1.x * w1.x + a1.y * w1.y + a1.z * w1.z + a1.w * w1.w;
    acc = wave_sum(acc);
    if (lane == 0) style[out] = acc + affine_b[c];
}

// Fused: W2[o][c] = sum_kk weight[o,c,:,:]^2  AND  wbf bf16 repack (swizzle baked).
// wbf[(t*8+q)][oc][64]: 16B sub-block s of row oc stored at position s ^ (oc&7).
__global__ void w2wbf_kernel(const float* __restrict__ weight,
                             float* __restrict__ W2,
                             unsigned short* __restrict__ wbf) {
    const int idx = blockIdx.x * 256 + threadIdx.x;   // 262144 = oc*512 + c
    const int oc = idx >> 9, c = idx & 511;
    const int q = c >> 6, c_local = c & 63;
    const int s = c_local >> 3, j = c_local & 7;
    const int pos = ((s ^ (oc & 7)) << 3) | j;
    const float* p = weight + (size_t)idx * 9;
    float ss = 0.f;
    #pragma unroll
    for (int t = 0; t < 9; ++t) {
        const float v = p[t];
        ss += v * v;
        wbf[((size_t)(t * 8 + q) * 512 + oc) * 64 + pos] = f2bf(v);
    }
    W2[idx] = ss;
}

// d[b][o] = rsqrt(sum_c style[b,c]^2 * W2[o,c] + eps); wave-per-output
__global__ void d_kernel(const float* __restrict__ style,
                         const float* __restrict__ W2,
                         float* __restrict__ dcoef) {
    const int out = blockIdx.x * 4 + (threadIdx.x >> 6);
    const int lane = threadIdx.x & 63;
    const int b = out >> 9, o = out & 511;
    const float4 s0 = *(const float4*)(style + (size_t)b * 512 + lane * 8);
    const float4 s1 = *(const float4*)(style + (size_t)b * 512 + lane * 8 + 4);
    const float4 v0 = *(const float4*)(W2 + (size_t)o * 512 + lane * 8);
    const float4 v1 = *(const float4*)(W2 + (size_t)o * 512 + lane * 8 + 4);
    float acc = s0.x * s0.x * v0.x + s0.y * s0.y * v0.y
              + s0.z * s0.z * v0.z + s0.w * s0.w * v0.w
              + s1.x * s1.x * v1.x + s1.y * s1.y * v1.y
              + s1.z * s1.z * v1.z + s1.w * s1.w * v1.w;
    acc = wave_sum(acc);
    if (lane == 0) dcoef[out] = rsqrtf(acc + 1e-8f);
}

// zero only the 132-cell pad border of xs[b][34][34][512]
__global__ void border_kernel(unsigned short* __restrict__ xs) {
    const int idx = blockIdx.x * 256 + threadIdx.x;   // 16*132*128 = 270336
    const int b = idx / (132 * 128);
    const int r_ = idx - b * (132 * 128);
    const int cell = r_ >> 7, t = r_ & 127;
    int rr, cc;
    if (cell < 34)      { rr = 0;  cc = cell; }
    else if (cell < 68) { rr = 33; cc = cell - 34; }
    else { const int jj = cell - 68; rr = 1 + (jj >> 1); cc = (jj & 1) ? 33 : 0; }
    us4 z = (us4){0, 0, 0, 0};
    *(us4*)(xs + (((size_t)b * 34 + rr) * 34 + cc) * 512 + t * 4) = z;
}

// xs_pad[b][34][34][512] bf16 (NHWC): interior [h+1][w+1][c] = x[b,c,h,w]*style[b,c]
__global__ void xspad_kernel(const float* __restrict__ x,
                             const float* __restrict__ style,
                             unsigned short* __restrict__ xs) {
    __shared__ __align__(16) unsigned short tile[128][36];
    const int b = blockIdx.z, h = blockIdx.y, c0 = blockIdx.x * 128;
    const int tid = threadIdx.x;               // 256
    #pragma unroll
    for (int it = 0; it < 4; ++it) {
        const int e = it * 256 + tid;
        const int ch = e >> 3, w4 = e & 7;
        const float4 v = *(const float4*)(x + (((size_t)b * 512 + c0 + ch) * 32 + h) * 32 + w4 * 4);
        const float sv = style[b * 512 + c0 + ch];
        us4 o;
        o.x = f2bf(v.x * sv); o.y = f2bf(v.y * sv);
        o.z = f2bf(v.z * sv); o.w = f2bf(v.w * sv);
        *(us4*)&tile[ch][w4 * 4] = o;
    }
    __syncthreads();
    #pragma unroll
    for (int it = 0; it < 2; ++it) {
        const int e = it * 256 + tid;
        const int cq = e & 15, w_ = e >> 4;
        us8 o;
        #pragma unroll
        for (int i = 0; i < 8; ++i) o[i] = tile[cq * 8 + i][w_];
        *(us8*)(xs + (((size_t)b * 34 + (h + 1)) * 34 + (w_ + 1)) * 512 + c0 + cq * 8) = o;
    }
}

// ---------- main conv ----------
// Implicit GEMM, BM=128(oc) x BN=256(px), BK=64, 72 K-tiles, 8 waves (2M x 4N).
// A: direct global->reg from pre-swizzled wbf (lane-constant offsets).
// B: 3-buffer LDS (32KB each), 2-tile-deep gload_lds prefetch.
// Sync: one raw s_barrier per K-tile; compiler emits counted vmcnt/lgkm waits
// (its wait for A(t) regs necessarily drains stage(t+1), older in the FIFO).
#define LDS_RD(off) (*(const bfx8*)(lds + (off)))
#define MFMA(a, bb, c) __builtin_amdgcn_mfma_f32_16x16x32_bf16((a), (bb), (c), 0, 0, 0)

__global__ __launch_bounds__(512, 2) void conv_kernel(
    const unsigned short* __restrict__ wbf,
    const unsigned short* __restrict__ xs,
    const float* __restrict__ dcoef,
    float* __restrict__ out) {
    __shared__ __align__(16) char lds[98304];       // 3 x 32768 (B tiles only)

    // T1: XCD-bijective remap (256 = 8 XCD x 32). XCD k owns batches {2k,2k+1}.
    const int id = blockIdx.x;
    const int wid = (id & 7) * 32 + (id >> 3);
    const int b = wid >> 4;
    const int oc0 = ((wid >> 2) & 3) << 7;
    const int n0  = (wid & 3) << 8;

    const int tid = threadIdx.x;
    const int lane = tid & 63;
    const int wv = tid >> 6;            // 0..7
    const int wr = wv >> 2, wc = wv & 3;
    const int l7 = lane & 7, l15 = lane & 15;

    // B fragment-read constants
    const int swz0 = ((lane >> 4) ^ l7) << 4;          // ks=0
    const int swz1 = (((lane >> 4) + 4) ^ l7) << 4;    // ks=1
    const int brow = (wc * 64 + l15) * 128;            // + ni*2048 + swz + co

    // A direct-load constants (wbf pre-swizzled; row&7 == l7 for all mi)
    const char* wbf8 = (const char*)wbf;
    int aofs0[4], aofs1[4];
    #pragma unroll
    for (int mi = 0; mi < 4; ++mi) {
        const int row = oc0 + wr * 64 + mi * 16 + l15;
        aofs0[mi] = row * 128 + (((lane >> 4)    ) ^ l7) * 16;
        aofs1[mi] = row * 128 + (((lane >> 4) + 4) ^ l7) * 16;
    }

    // B staging constants (wave-uniform LDS dst base; lane x 16B implicit)
    const int lsub = lane >> 3;                        // row-within-segment
    const int sx = l7 ^ lsub;                          // source sub-block swizzle
    size_t bbase[4]; int bdst[4];
    const size_t xsb = (size_t)b * (34 * 34 * 512);
    #pragma unroll
    for (int i = 0; i < 4; ++i) {
        const int p = wv * 32 + i * 8 + lsub;          // pixel row 0..255
        const int n = n0 + p;
        bbase[i] = xsb + ((size_t)(n >> 5) * 34 + (n & 31)) * 512 + sx * 8;
        bdst[i] = (wv * 4 + i) * 1024;
    }

#define STAGE_B(sh, bo) do { \
        gload_lds16(xs + bbase[0] + (sh), lds + (bo) + bdst[0]); \
        gload_lds16(xs + bbase[1] + (sh), lds + (bo) + bdst[1]); \
        gload_lds16(xs + bbase[2] + (sh), lds + (bo) + bdst[2]); \
        gload_lds16(xs + bbase[3] + (sh), lds + (bo) + bdst[3]); } while (0)
#define BARRIER() __builtin_amdgcn_s_barrier()

    f32x4 acc[4][4];
    #pragma unroll
    for (int i = 0; i < 4; ++i)
        #pragma unroll
        for (int j = 0; j < 4; ++j) acc[i][j] = (f32x4){0.f, 0.f, 0.f, 0.f};

    // prologue: stage B tiles 0 and 1
    STAGE_B(0, 0);
    STAGE_B(64, 32768);
    asm volatile("s_waitcnt vmcnt(4)" ::: "memory");   // tile 0 landed
    BARRIER();

    int co = 0;
    for (int t = 0; t < 72; ++t) {
        int so = co + 65536; if (so >= 98304) so -= 98304;     // buf for tile t+2
        const bool pf = (t < 70);
        const int sh2 = pf ? shift_of(t + 2) : 0;

        bfx8 af0[4], af1[4], bf0[4], bf1[4];

        // B fragment reads (compiler inserts counted lgkm waits before MFMAs)
        #pragma unroll
        for (int ni = 0; ni < 4; ++ni) bf0[ni] = LDS_RD(co + brow + ni * 2048 + swz0);
        #pragma unroll
        for (int ni = 0; ni < 4; ++ni) bf1[ni] = LDS_RD(co + brow + ni * 2048 + swz1);

        // A fragments: direct global->reg (L1-served; counted vmcnt waits by
        // compiler — these also drain the older stage(t+1) before the MFMAs).
        const char* ap = wbf8 + (size_t)t * 65536;
        #pragma unroll
        for (int mi = 0; mi < 4; ++mi) af0[mi] = *(const bfx8*)(ap + aofs0[mi]);
        #pragma unroll
        for (int mi = 0; mi < 4; ++mi) af1[mi] = *(const bfx8*)(ap + aofs1[mi]);

        // issue prefetch for tile t+2 (stays in flight through the MFMAs)
        if (pf) STAGE_B(sh2, so);

        __builtin_amdgcn_s_setprio(1);
        #pragma unroll
        for (int ni = 0; ni < 4; ++ni)
            #pragma unroll
            for (int mi = 0; mi < 4; ++mi)
                acc[mi][ni] = MFMA(af0[mi], bf0[ni], acc[mi][ni]);
        #pragma unroll
        for (int ni = 0; ni < 4; ++ni)
            #pragma unroll
            for (int mi = 0; mi < 4; ++mi)
                acc[mi][ni] = MFMA(af1[mi], bf1[ni], acc[mi][ni]);
        __builtin_amdgcn_s_setprio(0);

        BARRIER();
        co += 32768; if (co >= 98304) co -= 98304;
    }

    // epilogue: scale by demod d[b][oc], write fp32 NCHW
    const int r4 = (lane >> 4) * 4;
    #pragma unroll
    for (int mi = 0; mi < 4; ++mi) {
        #pragma unroll
        for (int rr = 0; rr < 4; ++rr) {
            const int ocr = oc0 + wr * 64 + mi * 16 + r4 + rr;
            const float dv = dcoef[b * 512 + ocr];
            float* orow = out + ((size_t)b * 512 + ocr) * 1024 + n0 + wc * 64 + l15;
            #pragma unroll
            for (int ni = 0; ni < 4; ++ni)
                orow[ni * 16] = acc[mi][ni][rr] * dv;
        }
    }
}

// ---------- launch ----------
extern "C" void kernel_launch(void* const* d_in, const int* in_sizes, int n_in,
                              void* d_out, int out_size, void* d_ws, size_t ws_size,
                              hipStream_t stream) {
    const float* x        = (const float*)d_in[0];   // (16,512,32,32)
    const float* w        = (const float*)d_in[1];   // (16,512)
    const float* weight   = (const float*)d_in[2];   // (512,512,3,3)
    const float* affine_w = (const float*)d_in[3];   // (512,512)
    const float* affine_b = (const float*)d_in[4];   // (512,)
    float* out = (float*)d_out;

    char* ws = (char*)d_ws;
    float*          style = (float*)(ws + 0);                 // 32 KB
    float*          W2    = (float*)(ws + 0x8000);            // 1 MB
    float*          dcoef = (float*)(ws + 0x108000);          // 32 KB
    unsigned short* wbf   = (unsigned short*)(ws + 0x110000); // 4.5 MB
    unsigned short* xs    = (unsigned short*)(ws + 0x590000); // 18.1 MB

    style_kernel<<<2048, 256, 0, stream>>>(w, affine_w, affine_b, style);
    w2wbf_kernel<<<1024, 256, 0, stream>>>(weight, W2, wbf);
    d_kernel<<<2048, 256, 0, stream>>>(style, W2, dcoef);
    border_kernel<<<1056, 256, 0, stream>>>(xs);
    xspad_kernel<<<dim3(4, 32, 16), 256, 0, stream>>>(x, style, xs);
    conv_kernel<<<256, 512, 0, stream>>>(wbf, xs, dcoef, out);
}

// Round 8
// 129.260 us; speedup vs baseline: 1.0517x; 1.0517x over previous
//
#include <hip/hip_runtime.h>

// ModConv: y[b,o,p] = d[b,o] * sum_{c,tap} weight[o,c,tap] * style[b,c] * x[b,c,p+tap]
// Prologue (style, W2+wbf fused, d, border-zero, xspad) + bf16 MFMA implicit-GEMM conv.
// Conv: A (weights) global->VGPR prefetched ONE TILE AHEAD (double-buffered regs);
// B (pixels) via swizzled gload_lds 3-buffer pipeline; one barrier per K-tile;
// explicit counted vmcnt(16)/(12) keeps both pipelines in flight (T1+T2+T4+T5+T14).

typedef __attribute__((ext_vector_type(8))) short bfx8;
typedef __attribute__((ext_vector_type(4))) float f32x4;
typedef __attribute__((ext_vector_type(4))) unsigned short us4;
typedef __attribute__((ext_vector_type(8))) unsigned short us8;

__device__ __forceinline__ unsigned short f2bf(float f) {
    unsigned int u = __builtin_bit_cast(unsigned int, f);
    u += 0x7FFFu + ((u >> 16) & 1u);          // round-to-nearest-even
    return (unsigned short)(u >> 16);
}

__device__ __forceinline__ void gload_lds16(const void* g, void* l) {
    __builtin_amdgcn_global_load_lds(
        (const __attribute__((address_space(1))) unsigned int*)g,
        (__attribute__((address_space(3))) unsigned int*)l,
        16, 0, 0);
}

__device__ __forceinline__ float wave_sum(float v) {
    #pragma unroll
    for (int m = 1; m < 64; m <<= 1) v += __shfl_xor(v, m, 64);
    return v;
}

__device__ __forceinline__ int shift_of(int t) {
    const int tap = t >> 3, q = t & 7;
    const int ky = tap / 3, kx = tap - ky * 3;
    return (ky * 34 + kx) * 512 + q * 64;
}

// ---------- prologue ----------

// style[b][c] = dot(w[b,:], affine_w[c,:]) + affine_b[c]; wave-per-output (8192 waves)
__global__ void style_kernel(const float* __restrict__ w,
                             const float* __restrict__ affine_w,
                             const float* __restrict__ affine_b,
                             float* __restrict__ style) {
    const int out = blockIdx.x * 4 + (threadIdx.x >> 6);
    const int lane = threadIdx.x & 63;
    const int b = out >> 9, c = out & 511;
    const float4 a0 = *(const float4*)(affine_w + (size_t)c * 512 + lane * 8);
    const float4 a1 = *(const float4*)(affine_w + (size_t)c * 512 + lane * 8 + 4);
    const float4 w0 = *(const float4*)(w + (size_t)b * 512 + lane * 8);
    const float4 w1 = *(const float4*)(w + (size_t)b * 512 + lane * 8 + 4);
    float acc = a0.x * w0.x + a0.y * w0.y + a0.z * w0.z + a0.w * w0.w
              + a1.x * w1.x + a1.y * w1.y + a1.z * w1.z + a1.w * w1.w;
    acc = wave_sum(acc);
    if (lane == 0) style[out] = acc + affine_b[c];
}

// Fused: W2[o][c] = sum_kk weight[o,c,:,:]^2  AND  wbf bf16 repack (swizzle baked).
// wbf[(t*8+q)][oc][64]: 16B sub-block s of row oc stored at position s ^ (oc&7).
__global__ void w2wbf_kernel(const float* __restrict__ weight,
                             float* __restrict__ W2,
                             unsigned short* __restrict__ wbf) {
    const int idx = blockIdx.x * 256 + threadIdx.x;   // 262144 = oc*512 + c
    const int oc = idx >> 9, c = idx & 511;
    const int q = c >> 6, c_local = c & 63;
    const int s = c_local >> 3, j = c_local & 7;
    const int pos = ((s ^ (oc & 7)) << 3) | j;
    const float* p = weight + (size_t)idx * 9;
    float ss = 0.f;
    #pragma unroll
    for (int t = 0; t < 9; ++t) {
        const float v = p[t];
        ss += v * v;
        wbf[((size_t)(t * 8 + q) * 512 + oc) * 64 + pos] = f2bf(v);
    }
    W2[idx] = ss;
}

// d[b][o] = rsqrt(sum_c style[b,c]^2 * W2[o,c] + eps); wave-per-output
__global__ void d_kernel(const float* __restrict__ style,
                         const float* __restrict__ W2,
                         float* __restrict__ dcoef) {
    const int out = blockIdx.x * 4 + (threadIdx.x >> 6);
    const int lane = threadIdx.x & 63;
    const int b = out >> 9, o = out & 511;
    const float4 s0 = *(const float4*)(style + (size_t)b * 512 + lane * 8);
    const float4 s1 = *(const float4*)(style + (size_t)b * 512 + lane * 8 + 4);
    const float4 v0 = *(const float4*)(W2 + (size_t)o * 512 + lane * 8);
    const float4 v1 = *(const float4*)(W2 + (size_t)o * 512 + lane * 8 + 4);
    float acc = s0.x * s0.x * v0.x + s0.y * s0.y * v0.y
              + s0.z * s0.z * v0.z + s0.w * s0.w * v0.w
              + s1.x * s1.x * v1.x + s1.y * s1.y * v1.y
              + s1.z * s1.z * v1.z + s1.w * s1.w * v1.w;
    acc = wave_sum(acc);
    if (lane == 0) dcoef[out] = rsqrtf(acc + 1e-8f);
}

// zero only the 132-cell pad border of xs[b][34][34][512]
__global__ void border_kernel(unsigned short* __restrict__ xs) {
    const int idx = blockIdx.x * 256 + threadIdx.x;   // 16*132*128 = 270336
    const int b = idx / (132 * 128);
    const int r_ = idx - b * (132 * 128);
    const int cell = r_ >> 7, t = r_ & 127;
    int rr, cc;
    if (cell < 34)      { rr = 0;  cc = cell; }
    else if (cell < 68) { rr = 33; cc = cell - 34; }
    else { const int jj = cell - 68; rr = 1 + (jj >> 1); cc = (jj & 1) ? 33 : 0; }
    us4 z = (us4){0, 0, 0, 0};
    *(us4*)(xs + (((size_t)b * 34 + rr) * 34 + cc) * 512 + t * 4) = z;
}

// xs_pad[b][34][34][512] bf16 (NHWC): interior [h+1][w+1][c] = x[b,c,h,w]*style[b,c]
__global__ void xspad_kernel(const float* __restrict__ x,
                             const float* __restrict__ style,
                             unsigned short* __restrict__ xs) {
    __shared__ __align__(16) unsigned short tile[128][36];
    const int b = blockIdx.z, h = blockIdx.y, c0 = blockIdx.x * 128;
    const int tid = threadIdx.x;               // 256
    #pragma unroll
    for (int it = 0; it < 4; ++it) {
        const int e = it * 256 + tid;
        const int ch = e >> 3, w4 = e & 7;
        const float4 v = *(const float4*)(x + (((size_t)b * 512 + c0 + ch) * 32 + h) * 32 + w4 * 4);
        const float sv = style[b * 512 + c0 + ch];
        us4 o;
        o.x = f2bf(v.x * sv); o.y = f2bf(v.y * sv);
        o.z = f2bf(v.z * sv); o.w = f2bf(v.w * sv);
        *(us4*)&tile[ch][w4 * 4] = o;
    }
    __syncthreads();
    #pragma unroll
    for (int it = 0; it < 2; ++it) {
        const int e = it * 256 + tid;
        const int cq = e & 15, w_ = e >> 4;
        us8 o;
        #pragma unroll
        for (int i = 0; i < 8; ++i) o[i] = tile[cq * 8 + i][w_];
        *(us8*)(xs + (((size_t)b * 34 + (h + 1)) * 34 + (w_ + 1)) * 512 + c0 + cq * 8) = o;
    }
}

// ---------- main conv ----------
// Implicit GEMM, BM=128(oc) x BN=256(px), BK=64, 72 K-tiles, 8 waves (2M x 4N).
// A: global->reg, prefetched 1 tile ahead into double-buffered named reg arrays.
// B: 3-buffer LDS (32KB each), 2-tile-deep gload_lds prefetch.
// vmcnt FIFO (S=stage 4 ops, L=aload 8 ops; order ...L(t),S(t+1),L(t+1),S(t+2)):
//   before MFMA(t):  drain L(t)   -> leave S(t+1)+L(t+1)+S(t+2) = vmcnt(16)
//   before barrier:  drain S(t+1) -> leave L(t+1)+S(t+2)        = vmcnt(12)
//   t=70: 12/8;  t=71: 0/-.
#define LDS_RD(off) (*(const bfx8*)(lds + (off)))
#define MFMA(a, bb, c) __builtin_amdgcn_mfma_f32_16x16x32_bf16((a), (bb), (c), 0, 0, 0)

__global__ __launch_bounds__(512, 4) void conv_kernel(
    const unsigned short* __restrict__ wbf,
    const unsigned short* __restrict__ xs,
    const float* __restrict__ dcoef,
    float* __restrict__ out) {
    __shared__ __align__(16) char lds[98304];       // 3 x 32768 (B tiles only)

    // T1: XCD-bijective remap (256 = 8 XCD x 32). XCD k owns batches {2k,2k+1}.
    const int id = blockIdx.x;
    const int wid = (id & 7) * 32 + (id >> 3);
    const int b = wid >> 4;
    const int oc0 = ((wid >> 2) & 3) << 7;
    const int n0  = (wid & 3) << 8;

    const int tid = threadIdx.x;
    const int lane = tid & 63;
    const int wv = tid >> 6;            // 0..7
    const int wr = wv >> 2, wc = wv & 3;
    const int l7 = lane & 7, l15 = lane & 15;

    // B fragment-read constants
    const int swz0 = ((lane >> 4) ^ l7) << 4;          // ks=0
    const int swz1 = (((lane >> 4) + 4) ^ l7) << 4;    // ks=1
    const int brow = (wc * 64 + l15) * 128;            // + ni*2048 + swz + co

    // A direct-load constants (wbf pre-swizzled in memory)
    const char* wbf8 = (const char*)wbf;
    int aofs0[4], aofs1[4];
    #pragma unroll
    for (int mi = 0; mi < 4; ++mi) {
        const int row = oc0 + wr * 64 + mi * 16 + l15;
        aofs0[mi] = row * 128 + (((lane >> 4)    ) ^ l7) * 16;
        aofs1[mi] = row * 128 + (((lane >> 4) + 4) ^ l7) * 16;
    }

    // B staging constants (wave-uniform LDS dst base; lane x 16B implicit)
    const int lsub = lane >> 3;                        // row-within-segment
    const int sx = l7 ^ lsub;                          // source sub-block swizzle
    size_t bbase[4]; int bdst[4];
    const size_t xsb = (size_t)b * (34 * 34 * 512);
    #pragma unroll
    for (int i = 0; i < 4; ++i) {
        const int p = wv * 32 + i * 8 + lsub;          // pixel row 0..255
        const int n = n0 + p;
        bbase[i] = xsb + ((size_t)(n >> 5) * 34 + (n & 31)) * 512 + sx * 8;
        bdst[i] = (wv * 4 + i) * 1024;
    }

#define STAGE_B(sh, bo) do { \
        gload_lds16(xs + bbase[0] + (sh), lds + (bo) + bdst[0]); \
        gload_lds16(xs + bbase[1] + (sh), lds + (bo) + bdst[1]); \
        gload_lds16(xs + bbase[2] + (sh), lds + (bo) + bdst[2]); \
        gload_lds16(xs + bbase[3] + (sh), lds + (bo) + bdst[3]); } while (0)
#define ALOAD(dst, tt) do { \
        const char* ap_ = wbf8 + (size_t)(tt) * 65536; \
        _Pragma("unroll") \
        for (int mi_ = 0; mi_ < 4; ++mi_) dst[mi_]     = *(const bfx8*)(ap_ + aofs0[mi_]); \
        _Pragma("unroll") \
        for (int mi_ = 0; mi_ < 4; ++mi_) dst[mi_ + 4] = *(const bfx8*)(ap_ + aofs1[mi_]); } while (0)
#define BARRIER() __builtin_amdgcn_s_barrier()

    f32x4 acc[4][4];
    #pragma unroll
    for (int i = 0; i < 4; ++i)
        #pragma unroll
        for (int j = 0; j < 4; ++j) acc[i][j] = (f32x4){0.f, 0.f, 0.f, 0.f};

    bfx8 afA[8], afB[8];

    // prologue: S(0), L(0)->afA, S(1); drain S0+L0 (leave S1)
    STAGE_B(0, 0);
    ALOAD(afA, 0);
    STAGE_B(64, 32768);
    asm volatile("s_waitcnt vmcnt(4)" ::: "memory");
    BARRIER();

    int co = 0;

#define CONV_BODY(T, AFC, AFN) do { \
        const int t_ = (T); \
        int so_ = co + 65536; if (so_ >= 98304) so_ -= 98304; \
        bfx8 bf0[4], bf1[4]; \
        _Pragma("unroll") \
        for (int ni_ = 0; ni_ < 4; ++ni_) bf0[ni_] = LDS_RD(co + brow + ni_ * 2048 + swz0); \
        _Pragma("unroll") \
        for (int ni_ = 0; ni_ < 4; ++ni_) bf1[ni_] = LDS_RD(co + brow + ni_ * 2048 + swz1); \
        if (t_ < 71) ALOAD(AFN, t_ + 1); \
        if (t_ < 70) { const int sh2_ = shift_of(t_ + 2); STAGE_B(sh2_, so_); } \
        if (t_ < 70)      asm volatile("s_waitcnt vmcnt(16)" ::: "memory"); \
        else if (t_ == 70) asm volatile("s_waitcnt vmcnt(12)" ::: "memory"); \
        else               asm volatile("s_waitcnt vmcnt(0)"  ::: "memory"); \
        __builtin_amdgcn_s_setprio(1); \
        _Pragma("unroll") \
        for (int ni_ = 0; ni_ < 4; ++ni_) \
            _Pragma("unroll") \
            for (int mi_ = 0; mi_ < 4; ++mi_) \
                acc[mi_][ni_] = MFMA(AFC[mi_], bf0[ni_], acc[mi_][ni_]); \
        _Pragma("unroll") \
        for (int ni_ = 0; ni_ < 4; ++ni_) \
            _Pragma("unroll") \
            for (int mi_ = 0; mi_ < 4; ++mi_) \
                acc[mi_][ni_] = MFMA(AFC[mi_ + 4], bf1[ni_], acc[mi_][ni_]); \
        __builtin_amdgcn_s_setprio(0); \
        if (t_ < 70)      asm volatile("s_waitcnt vmcnt(12)" ::: "memory"); \
        else if (t_ == 70) asm volatile("s_waitcnt vmcnt(8)"  ::: "memory"); \
        BARRIER(); \
        co += 32768; if (co >= 98304) co -= 98304; \
    } while (0)

    #pragma unroll 1
    for (int tt = 0; tt < 36; ++tt) {
        CONV_BODY(2 * tt,     afA, afB);
        CONV_BODY(2 * tt + 1, afB, afA);
    }

    // epilogue: scale by demod d[b][oc], write fp32 NCHW
    const int r4 = (lane >> 4) * 4;
    #pragma unroll
    for (int mi = 0; mi < 4; ++mi) {
        #pragma unroll
        for (int rr = 0; rr < 4; ++rr) {
            const int ocr = oc0 + wr * 64 + mi * 16 + r4 + rr;
            const float dv = dcoef[b * 512 + ocr];
            float* orow = out + ((size_t)b * 512 + ocr) * 1024 + n0 + wc * 64 + l15;
            #pragma unroll
            for (int ni = 0; ni < 4; ++ni)
                orow[ni * 16] = acc[mi][ni][rr] * dv;
        }
    }
}

// ---------- launch ----------
extern "C" void kernel_launch(void* const* d_in, const int* in_sizes, int n_in,
                              void* d_out, int out_size, void* d_ws, size_t ws_size,
                              hipStream_t stream) {
    const float* x        = (const float*)d_in[0];   // (16,512,32,32)
    const float* w        = (const float*)d_in[1];   // (16,512)
    const float* weight   = (const float*)d_in[2];   // (512,512,3,3)
    const float* affine_w = (const float*)d_in[3];   // (512,512)
    const float* affine_b = (const float*)d_in[4];   // (512,)
    float* out = (float*)d_out;

    char* ws = (char*)d_ws;
    float*          style = (float*)(ws + 0);                 // 32 KB
    float*          W2    = (float*)(ws + 0x8000);            // 1 MB
    float*          dcoef = (float*)(ws + 0x108000);          // 32 KB
    unsigned short* wbf   = (unsigned short*)(ws + 0x110000); // 4.5 MB
    unsigned short* xs    = (unsigned short*)(ws + 0x590000); // 18.1 MB

    style_kernel<<<2048, 256, 0, stream>>>(w, affine_w, affine_b, style);
    w2wbf_kernel<<<1024, 256, 0, stream>>>(weight, W2, wbf);
    d_kernel<<<2048, 256, 0, stream>>>(style, W2, dcoef);
    border_kernel<<<1056, 256, 0, stream>>>(xs);
    xspad_kernel<<<dim3(4, 32, 16), 256, 0, stream>>>(x, style, xs);
    conv_kernel<<<256, 512, 0, stream>>>(wbf, xs, dcoef, out);
}

// Round 9
// 97.809 us; speedup vs baseline: 1.3899x; 1.3215x over previous
//
#include <hip/hip_runtime.h>

// ModConv: y[b,o,p] = d[b,o] * sum_{c,tap} weight[o,c,tap] * style[b,c] * x[b,c,p+tap]
// Prologue (style, W2+wbf fused, d, border-zero, xspad) + bf16 MFMA implicit-GEMM conv.
// Conv (round-6 LDS structure + fragment-level pipeline): A & B staged in 3-buffer
// LDS; each iter reads NEXT tile's fragments into alternate reg set while current
// tile's MFMAs run -> LDS-read pipe overlaps MFMA pipe (T1+T2+T4+T5).

typedef __attribute__((ext_vector_type(8))) short bfx8;
typedef __attribute__((ext_vector_type(4))) float f32x4;
typedef __attribute__((ext_vector_type(4))) unsigned short us4;
typedef __attribute__((ext_vector_type(8))) unsigned short us8;

__device__ __forceinline__ unsigned short f2bf(float f) {
    unsigned int u = __builtin_bit_cast(unsigned int, f);
    u += 0x7FFFu + ((u >> 16) & 1u);          // round-to-nearest-even
    return (unsigned short)(u >> 16);
}

__device__ __forceinline__ void gload_lds16(const void* g, void* l) {
    __builtin_amdgcn_global_load_lds(
        (const __attribute__((address_space(1))) unsigned int*)g,
        (__attribute__((address_space(3))) unsigned int*)l,
        16, 0, 0);
}

__device__ __forceinline__ float wave_sum(float v) {
    #pragma unroll
    for (int m = 1; m < 64; m <<= 1) v += __shfl_xor(v, m, 64);
    return v;
}

__device__ __forceinline__ int shift_of(int t) {
    const int tap = t >> 3, q = t & 7;
    const int ky = tap / 3, kx = tap - ky * 3;
    return (ky * 34 + kx) * 512 + q * 64;
}

// ---------- prologue ----------

// style[b][c] = dot(w[b,:], affine_w[c,:]) + affine_b[c]; wave-per-output (8192 waves)
__global__ void style_kernel(const float* __restrict__ w,
                             const float* __restrict__ affine_w,
                             const float* __restrict__ affine_b,
                             float* __restrict__ style) {
    const int out = blockIdx.x * 4 + (threadIdx.x >> 6);
    const int lane = threadIdx.x & 63;
    const int b = out >> 9, c = out & 511;
    const float4 a0 = *(const float4*)(affine_w + (size_t)c * 512 + lane * 8);
    const float4 a1 = *(const float4*)(affine_w + (size_t)c * 512 + lane * 8 + 4);
    const float4 w0 = *(const float4*)(w + (size_t)b * 512 + lane * 8);
    const float4 w1 = *(const float4*)(w + (size_t)b * 512 + lane * 8 + 4);
    float acc = a0.x * w0.x + a0.y * w0.y + a0.z * w0.z + a0.w * w0.w
              + a1.x * w1.x + a1.y * w1.y + a1.z * w1.z + a1.w * w1.w;
    acc = wave_sum(acc);
    if (lane == 0) style[out] = acc + affine_b[c];
}

// Fused: W2[o][c] = sum_kk weight[o,c,:,:]^2  AND  wbf bf16 repack (swizzle baked).
// wbf[(t*8+q)][oc][64]: 16B sub-block s of row oc stored at position s ^ (oc&7).
__global__ void w2wbf_kernel(const float* __restrict__ weight,
                             float* __restrict__ W2,
                             unsigned short* __restrict__ wbf) {
    const int idx = blockIdx.x * 256 + threadIdx.x;   // 262144 = oc*512 + c
    const int oc = idx >> 9, c = idx & 511;
    const int q = c >> 6, c_local = c & 63;
    const int s = c_local >> 3, j = c_local & 7;
    const int pos = ((s ^ (oc & 7)) << 3) | j;
    const float* p = weight + (size_t)idx * 9;
    float ss = 0.f;
    #pragma unroll
    for (int t = 0; t < 9; ++t) {
        const float v = p[t];
        ss += v * v;
        wbf[((size_t)(t * 8 + q) * 512 + oc) * 64 + pos] = f2bf(v);
    }
    W2[idx] = ss;
}

// d[b][o] = rsqrt(sum_c style[b,c]^2 * W2[o,c] + eps); wave-per-output
__global__ void d_kernel(const float* __restrict__ style,
                         const float* __restrict__ W2,
                         float* __restrict__ dcoef) {
    const int out = blockIdx.x * 4 + (threadIdx.x >> 6);
    const int lane = threadIdx.x & 63;
    const int b = out >> 9, o = out & 511;
    const float4 s0 = *(const float4*)(style + (size_t)b * 512 + lane * 8);
    const float4 s1 = *(const float4*)(style + (size_t)b * 512 + lane * 8 + 4);
    const float4 v0 = *(const float4*)(W2 + (size_t)o * 512 + lane * 8);
    const float4 v1 = *(const float4*)(W2 + (size_t)o * 512 + lane * 8 + 4);
    float acc = s0.x * s0.x * v0.x + s0.y * s0.y * v0.y
              + s0.z * s0.z * v0.z + s0.w * s0.w * v0.w
              + s1.x * s1.x * v1.x + s1.y * s1.y * v1.y
              + s1.z * s1.z * v1.z + s1.w * s1.w * v1.w;
    acc = wave_sum(acc);
    if (lane == 0) dcoef[out] = rsqrtf(acc + 1e-8f);
}

// zero only the 132-cell pad border of xs[b][34][34][512]
__global__ void border_kernel(unsigned short* __restrict__ xs) {
    const int idx = blockIdx.x * 256 + threadIdx.x;   // 16*132*128 = 270336
    const int b = idx / (132 * 128);
    const int r_ = idx - b * (132 * 128);
    const int cell = r_ >> 7, t = r_ & 127;
    int rr, cc;
    if (cell < 34)      { rr = 0;  cc = cell; }
    else if (cell < 68) { rr = 33; cc = cell - 34; }
    else { const int jj = cell - 68; rr = 1 + (jj >> 1); cc = (jj & 1) ? 33 : 0; }
    us4 z = (us4){0, 0, 0, 0};
    *(us4*)(xs + (((size_t)b * 34 + rr) * 34 + cc) * 512 + t * 4) = z;
}

// xs_pad[b][34][34][512] bf16 (NHWC): interior [h+1][w+1][c] = x[b,c,h,w]*style[b,c]
__global__ void xspad_kernel(const float* __restrict__ x,
                             const float* __restrict__ style,
                             unsigned short* __restrict__ xs) {
    __shared__ __align__(16) unsigned short tile[128][36];
    const int b = blockIdx.z, h = blockIdx.y, c0 = blockIdx.x * 128;
    const int tid = threadIdx.x;               // 256
    #pragma unroll
    for (int it = 0; it < 4; ++it) {
        const int e = it * 256 + tid;
        const int ch = e >> 3, w4 = e & 7;
        const float4 v = *(const float4*)(x + (((size_t)b * 512 + c0 + ch) * 32 + h) * 32 + w4 * 4);
        const float sv = style[b * 512 + c0 + ch];
        us4 o;
        o.x = f2bf(v.x * sv); o.y = f2bf(v.y * sv);
        o.z = f2bf(v.z * sv); o.w = f2bf(v.w * sv);
        *(us4*)&tile[ch][w4 * 4] = o;
    }
    __syncthreads();
    #pragma unroll
    for (int it = 0; it < 2; ++it) {
        const int e = it * 256 + tid;
        const int cq = e & 15, w_ = e >> 4;
        us8 o;
        #pragma unroll
        for (int i = 0; i < 8; ++i) o[i] = tile[cq * 8 + i][w_];
        *(us8*)(xs + (((size_t)b * 34 + (h + 1)) * 34 + (w_ + 1)) * 512 + c0 + cq * 8) = o;
    }
}

// ---------- main conv ----------
// Implicit GEMM, BM=128(oc) x BN=256(px), BK=64, 72 K-tiles, 8 waves (2M x 4N),
// 3-buffer LDS (48KB each: A 16KB + B 32KB), 2-tile-deep stage prefetch.
// Iter t: vmcnt(0) [only S(t+1) outstanding] -> barrier -> STAGE(t+2) ->
//         ds_reads for tile t+1 (alternate reg set) -> 32 MFMAs on tile t regs.
#define LDS_RD(off) (*(const bfx8*)(lds + (off)))
#define MFMA(a, bb, c) __builtin_amdgcn_mfma_f32_16x16x32_bf16((a), (bb), (c), 0, 0, 0)

__global__ __launch_bounds__(512, 2) void conv_kernel(
    const unsigned short* __restrict__ wbf,
    const unsigned short* __restrict__ xs,
    const float* __restrict__ dcoef,
    float* __restrict__ out) {
    __shared__ __align__(16) char lds[147456];      // 3 x 49152 (A 16KB + B 32KB)

    // T1: XCD-bijective remap (256 = 8 XCD x 32). XCD k owns batches {2k,2k+1}.
    const int id = blockIdx.x;
    const int wid = (id & 7) * 32 + (id >> 3);
    const int b = wid >> 4;
    const int oc0 = ((wid >> 2) & 3) << 7;
    const int n0  = (wid & 3) << 8;

    const int tid = threadIdx.x;
    const int lane = tid & 63;
    const int wv = tid >> 6;            // 0..7
    const int wr = wv >> 2, wc = wv & 3;
    const int l7 = lane & 7, l15 = lane & 15;

    // fragment-read constants
    const int swz0 = ((lane >> 4) ^ l7) << 4;          // ks=0
    const int swz1 = (((lane >> 4) + 4) ^ l7) << 4;    // ks=1
    const int arow = (wr * 64 + l15) * 128;            // + mi*2048 + swz + buf
    const int brow = 16384 + (wc * 64 + l15) * 128;    // + ni*2048 + swz + buf

    // staging constants (wave-uniform LDS dst base; lane x 16B implicit)
    const int lsub = lane >> 3;                        // row-within-segment
    const int sx = l7 ^ lsub;                          // source sub-block swizzle (B only)
    const int ra0 = wv * 16 + lsub, ra1 = ra0 + 8;     // A rows
    // A: wbf is PRE-swizzled in memory -> linear l7 source sub-block
    const int aoff0 = (oc0 + ra0) * 64 + l7 * 8;
    const int aoff1 = (oc0 + ra1) * 64 + l7 * 8;
    const int adst0 = (wv * 2) * 1024, adst1 = adst0 + 1024;
    size_t bbase[4]; int bdst[4];
    const size_t xsb = (size_t)b * (34 * 34 * 512);
    #pragma unroll
    for (int i = 0; i < 4; ++i) {
        const int p = wv * 32 + i * 8 + lsub;          // pixel row 0..255
        const int n = n0 + p;
        bbase[i] = xsb + ((size_t)(n >> 5) * 34 + (n & 31)) * 512 + sx * 8;
        bdst[i] = 16384 + (wv * 4 + i) * 1024;
    }

#define STAGE_ALL(tt, bo) do { \
        const unsigned short* wsrc_ = wbf + (size_t)(tt) * 32768; \
        const int sh_ = shift_of(tt); \
        gload_lds16(wsrc_ + aoff0, lds + (bo) + adst0); \
        gload_lds16(wsrc_ + aoff1, lds + (bo) + adst1); \
        gload_lds16(xs + bbase[0] + sh_, lds + (bo) + bdst[0]); \
        gload_lds16(xs + bbase[1] + sh_, lds + (bo) + bdst[1]); \
        gload_lds16(xs + bbase[2] + sh_, lds + (bo) + bdst[2]); \
        gload_lds16(xs + bbase[3] + sh_, lds + (bo) + bdst[3]); } while (0)

#define READS(S, cb) do { \
        _Pragma("unroll") \
        for (int mi_ = 0; mi_ < 4; ++mi_) a0##S[mi_] = LDS_RD((cb) + arow + mi_ * 2048 + swz0); \
        _Pragma("unroll") \
        for (int ni_ = 0; ni_ < 4; ++ni_) b0##S[ni_] = LDS_RD((cb) + brow + ni_ * 2048 + swz0); \
        _Pragma("unroll") \
        for (int mi_ = 0; mi_ < 4; ++mi_) a1##S[mi_] = LDS_RD((cb) + arow + mi_ * 2048 + swz1); \
        _Pragma("unroll") \
        for (int ni_ = 0; ni_ < 4; ++ni_) b1##S[ni_] = LDS_RD((cb) + brow + ni_ * 2048 + swz1); } while (0)

#define BARRIER() __builtin_amdgcn_s_barrier()

    f32x4 acc[4][4];
    #pragma unroll
    for (int i = 0; i < 4; ++i)
        #pragma unroll
        for (int j = 0; j < 4; ++j) acc[i][j] = (f32x4){0.f, 0.f, 0.f, 0.f};

    bfx8 a0A[4], a1A[4], b0A[4], b1A[4];
    bfx8 a0B[4], a1B[4], b0B[4], b1B[4];

    // prologue: stage tiles 0,1; wait tile 0; read tile 0 fragments into set A
    STAGE_ALL(0, 0);
    STAGE_ALL(1, 49152);
    asm volatile("s_waitcnt vmcnt(6)" ::: "memory");   // tile 0 landed
    BARRIER();
    READS(A, 0);

    int co = 0;

#define ITER(T, C, N) do { \
        const int t_ = (T); \
        int cn_ = co + 49152; if (cn_ >= 147456) cn_ -= 147456;   /* buf t+1 */ \
        int so_ = co + 98304; if (so_ >= 147456) so_ -= 147456;   /* buf t+2 */ \
        asm volatile("s_waitcnt vmcnt(0)" ::: "memory");          /* S(t+1) landed */ \
        BARRIER(); \
        if (t_ < 70) STAGE_ALL(t_ + 2, so_); \
        if (t_ < 71) READS(N, cn_); \
        __builtin_amdgcn_s_setprio(1); \
        _Pragma("unroll") \
        for (int ni_ = 0; ni_ < 4; ++ni_) \
            _Pragma("unroll") \
            for (int mi_ = 0; mi_ < 4; ++mi_) \
                acc[mi_][ni_] = MFMA(a0##C[mi_], b0##C[ni_], acc[mi_][ni_]); \
        _Pragma("unroll") \
        for (int ni_ = 0; ni_ < 4; ++ni_) \
            _Pragma("unroll") \
            for (int mi_ = 0; mi_ < 4; ++mi_) \
                acc[mi_][ni_] = MFMA(a1##C[mi_], b1##C[ni_], acc[mi_][ni_]); \
        __builtin_amdgcn_s_setprio(0); \
        co = cn_; \
    } while (0)

    #pragma unroll 1
    for (int tt = 0; tt < 36; ++tt) {
        ITER(2 * tt,     A, B);
        ITER(2 * tt + 1, B, A);
    }

    // epilogue: scale by demod d[b][oc], write fp32 NCHW
    const int r4 = (lane >> 4) * 4;
    #pragma unroll
    for (int mi = 0; mi < 4; ++mi) {
        #pragma unroll
        for (int rr = 0; rr < 4; ++rr) {
            const int ocr = oc0 + wr * 64 + mi * 16 + r4 + rr;
            const float dv = dcoef[b * 512 + ocr];
            float* orow = out + ((size_t)b * 512 + ocr) * 1024 + n0 + wc * 64 + l15;
            #pragma unroll
            for (int ni = 0; ni < 4; ++ni)
                orow[ni * 16] = acc[mi][ni][rr] * dv;
        }
    }
}

// ---------- launch ----------
extern "C" void kernel_launch(void* const* d_in, const int* in_sizes, int n_in,
                              void* d_out, int out_size, void* d_ws, size_t ws_size,
                              hipStream_t stream) {
    const float* x        = (const float*)d_in[0];   // (16,512,32,32)
    const float* w        = (const float*)d_in[1];   // (16,512)
    const float* weight   = (const float*)d_in[2];   // (512,512,3,3)
    const float* affine_w = (const float*)d_in[3];   // (512,512)
    const float* affine_b = (const float*)d_in[4];   // (512,)
    float* out = (float*)d_out;

    char* ws = (char*)d_ws;
    float*          style = (float*)(ws + 0);                 // 32 KB
    float*          W2    = (float*)(ws + 0x8000);            // 1 MB
    float*          dcoef = (float*)(ws + 0x108000);          // 32 KB
    unsigned short* wbf   = (unsigned short*)(ws + 0x110000); // 4.5 MB
    unsigned short* xs    = (unsigned short*)(ws + 0x590000); // 18.1 MB

    style_kernel<<<2048, 256, 0, stream>>>(w, affine_w, affine_b, style);
    w2wbf_kernel<<<1024, 256, 0, stream>>>(weight, W2, wbf);
    d_kernel<<<2048, 256, 0, stream>>>(style, W2, dcoef);
    border_kernel<<<1056, 256, 0, stream>>>(xs);
    xspad_kernel<<<dim3(4, 32, 16), 256, 0, stream>>>(x, style, xs);
    conv_kernel<<<256, 512, 0, stream>>>(wbf, xs, dcoef, out);
}

// Round 10
// 97.546 us; speedup vs baseline: 1.3937x; 1.0027x over previous
//
#include <hip/hip_runtime.h>

// ModConv: y[b,o,p] = d[b,o] * sum_{c,tap} weight[o,c,tap] * style[b,c] * x[b,c,p+tap]
// Prologue (style, W2+wbf fused, d, border-zero, xspad) + bf16 MFMA implicit-GEMM conv.
// Conv: 3-buffer LDS; each iter reads NEXT tile's fragments into alternate reg set,
// pinned BEFORE current tile's MFMAs via sched_barrier(0), so the LDS-read pipe
// (1536 cyc/tile) overlaps the MFMA pipe (1242 cyc/tile). launch_bounds(512,1)
// gives the allocator the 256-VGPR budget the double fragment set needs.

typedef __attribute__((ext_vector_type(8))) short bfx8;
typedef __attribute__((ext_vector_type(4))) float f32x4;
typedef __attribute__((ext_vector_type(4))) unsigned short us4;
typedef __attribute__((ext_vector_type(8))) unsigned short us8;

__device__ __forceinline__ unsigned short f2bf(float f) {
    unsigned int u = __builtin_bit_cast(unsigned int, f);
    u += 0x7FFFu + ((u >> 16) & 1u);          // round-to-nearest-even
    return (unsigned short)(u >> 16);
}

__device__ __forceinline__ void gload_lds16(const void* g, void* l) {
    __builtin_amdgcn_global_load_lds(
        (const __attribute__((address_space(1))) unsigned int*)g,
        (__attribute__((address_space(3))) unsigned int*)l,
        16, 0, 0);
}

__device__ __forceinline__ float wave_sum(float v) {
    #pragma unroll
    for (int m = 1; m < 64; m <<= 1) v += __shfl_xor(v, m, 64);
    return v;
}

__device__ __forceinline__ int shift_of(int t) {
    const int tap = t >> 3, q = t & 7;
    const int ky = tap / 3, kx = tap - ky * 3;
    return (ky * 34 + kx) * 512 + q * 64;
}

// ---------- prologue ----------

// style[b][c] = dot(w[b,:], affine_w[c,:]) + affine_b[c]; wave-per-output (8192 waves)
__global__ void style_kernel(const float* __restrict__ w,
                             const float* __restrict__ affine_w,
                             const float* __restrict__ affine_b,
                             float* __restrict__ style) {
    const int out = blockIdx.x * 4 + (threadIdx.x >> 6);
    const int lane = threadIdx.x & 63;
    const int b = out >> 9, c = out & 511;
    const float4 a0 = *(const float4*)(affine_w + (size_t)c * 512 + lane * 8);
    const float4 a1 = *(const float4*)(affine_w + (size_t)c * 512 + lane * 8 + 4);
    const float4 w0 = *(const float4*)(w + (size_t)b * 512 + lane * 8);
    const float4 w1 = *(const float4*)(w + (size_t)b * 512 + lane * 8 + 4);
    float acc = a0.x * w0.x + a0.y * w0.y + a0.z * w0.z + a0.w * w0.w
              + a1.x * w1.x + a1.y * w1.y + a1.z * w1.z + a1.w * w1.w;
    acc = wave_sum(acc);
    if (lane == 0) style[out] = acc + affine_b[c];
}

// Fused: W2[o][c] = sum_kk weight[o,c,:,:]^2  AND  wbf bf16 repack (swizzle baked).
// wbf[(t*8+q)][oc][64]: 16B sub-block s of row oc stored at position s ^ (oc&7).
__global__ void w2wbf_kernel(const float* __restrict__ weight,
                             float* __restrict__ W2,
                             unsigned short* __restrict__ wbf) {
    const int idx = blockIdx.x * 256 + threadIdx.x;   // 262144 = oc*512 + c
    const int oc = idx >> 9, c = idx & 511;
    const int q = c >> 6, c_local = c & 63;
    const int s = c_local >> 3, j = c_local & 7;
    const int pos = ((s ^ (oc & 7)) << 3) | j;
    const float* p = weight + (size_t)idx * 9;
    float ss = 0.f;
    #pragma unroll
    for (int t = 0; t < 9; ++t) {
        const float v = p[t];
        ss += v * v;
        wbf[((size_t)(t * 8 + q) * 512 + oc) * 64 + pos] = f2bf(v);
    }
    W2[idx] = ss;
}

// d[b][o] = rsqrt(sum_c style[b,c]^2 * W2[o,c] + eps); wave-per-output
__global__ void d_kernel(const float* __restrict__ style,
                         const float* __restrict__ W2,
                         float* __restrict__ dcoef) {
    const int out = blockIdx.x * 4 + (threadIdx.x >> 6);
    const int lane = threadIdx.x & 63;
    const int b = out >> 9, o = out & 511;
    const float4 s0 = *(const float4*)(style + (size_t)b * 512 + lane * 8);
    const float4 s1 = *(const float4*)(style + (size_t)b * 512 + lane * 8 + 4);
    const float4 v0 = *(const float4*)(W2 + (size_t)o * 512 + lane * 8);
    const float4 v1 = *(const float4*)(W2 + (size_t)o * 512 + lane * 8 + 4);
    float acc = s0.x * s0.x * v0.x + s0.y * s0.y * v0.y
              + s0.z * s0.z * v0.z + s0.w * s0.w * v0.w
              + s1.x * s1.x * v1.x + s1.y * s1.y * v1.y
              + s1.z * s1.z * v1.z + s1.w * s1.w * v1.w;
    acc = wave_sum(acc);
    if (lane == 0) dcoef[out] = rsqrtf(acc + 1e-8f);
}

// zero only the 132-cell pad border of xs[b][34][34][512]
__global__ void border_kernel(unsigned short* __restrict__ xs) {
    const int idx = blockIdx.x * 256 + threadIdx.x;   // 16*132*128 = 270336
    const int b = idx / (132 * 128);
    const int r_ = idx - b * (132 * 128);
    const int cell = r_ >> 7, t = r_ & 127;
    int rr, cc;
    if (cell < 34)      { rr = 0;  cc = cell; }
    else if (cell < 68) { rr = 33; cc = cell - 34; }
    else { const int jj = cell - 68; rr = 1 + (jj >> 1); cc = (jj & 1) ? 33 : 0; }
    us4 z = (us4){0, 0, 0, 0};
    *(us4*)(xs + (((size_t)b * 34 + rr) * 34 + cc) * 512 + t * 4) = z;
}

// xs_pad[b][34][34][512] bf16 (NHWC): interior [h+1][w+1][c] = x[b,c,h,w]*style[b,c]
__global__ void xspad_kernel(const float* __restrict__ x,
                             const float* __restrict__ style,
                             unsigned short* __restrict__ xs) {
    __shared__ __align__(16) unsigned short tile[128][36];
    const int b = blockIdx.z, h = blockIdx.y, c0 = blockIdx.x * 128;
    const int tid = threadIdx.x;               // 256
    #pragma unroll
    for (int it = 0; it < 4; ++it) {
        const int e = it * 256 + tid;
        const int ch = e >> 3, w4 = e & 7;
        const float4 v = *(const float4*)(x + (((size_t)b * 512 + c0 + ch) * 32 + h) * 32 + w4 * 4);
        const float sv = style[b * 512 + c0 + ch];
        us4 o;
        o.x = f2bf(v.x * sv); o.y = f2bf(v.y * sv);
        o.z = f2bf(v.z * sv); o.w = f2bf(v.w * sv);
        *(us4*)&tile[ch][w4 * 4] = o;
    }
    __syncthreads();
    #pragma unroll
    for (int it = 0; it < 2; ++it) {
        const int e = it * 256 + tid;
        const int cq = e & 15, w_ = e >> 4;
        us8 o;
        #pragma unroll
        for (int i = 0; i < 8; ++i) o[i] = tile[cq * 8 + i][w_];
        *(us8*)(xs + (((size_t)b * 34 + (h + 1)) * 34 + (w_ + 1)) * 512 + c0 + cq * 8) = o;
    }
}

// ---------- main conv ----------
// Implicit GEMM, BM=128(oc) x BN=256(px), BK=64, 72 K-tiles, 8 waves (2M x 4N),
// 3-buffer LDS (48KB each: A 16KB + B 32KB), 2-tile-deep stage prefetch.
// Iter t: vmcnt(0) [only S(t+1) outstanding] -> barrier -> STAGE(t+2) ->
//         ds_reads for tile t+1 (alternate reg set) -> sched_barrier(0) ->
//         32 MFMAs on tile t regs (overlap with the in-flight ds_reads).
#define LDS_RD(off) (*(const bfx8*)(lds + (off)))
#define MFMA(a, bb, c) __builtin_amdgcn_mfma_f32_16x16x32_bf16((a), (bb), (c), 0, 0, 0)

__global__ __launch_bounds__(512, 1) void conv_kernel(
    const unsigned short* __restrict__ wbf,
    const unsigned short* __restrict__ xs,
    const float* __restrict__ dcoef,
    float* __restrict__ out) {
    __shared__ __align__(16) char lds[147456];      // 3 x 49152 (A 16KB + B 32KB)

    // T1: XCD-bijective remap (256 = 8 XCD x 32). XCD k owns batches {2k,2k+1}.
    const int id = blockIdx.x;
    const int wid = (id & 7) * 32 + (id >> 3);
    const int b = wid >> 4;
    const int oc0 = ((wid >> 2) & 3) << 7;
    const int n0  = (wid & 3) << 8;

    const int tid = threadIdx.x;
    const int lane = tid & 63;
    const int wv = tid >> 6;            // 0..7
    const int wr = wv >> 2, wc = wv & 3;
    const int l7 = lane & 7, l15 = lane & 15;

    // fragment-read constants
    const int swz0 = ((lane >> 4) ^ l7) << 4;          // ks=0
    const int swz1 = (((lane >> 4) + 4) ^ l7) << 4;    // ks=1
    const int arow = (wr * 64 + l15) * 128;            // + mi*2048 + swz + buf
    const int brow = 16384 + (wc * 64 + l15) * 128;    // + ni*2048 + swz + buf

    // staging constants (wave-uniform LDS dst base; lane x 16B implicit)
    const int lsub = lane >> 3;                        // row-within-segment
    const int sx = l7 ^ lsub;                          // source sub-block swizzle (B only)
    const int ra0 = wv * 16 + lsub, ra1 = ra0 + 8;     // A rows
    // A: wbf is PRE-swizzled in memory -> linear l7 source sub-block
    const int aoff0 = (oc0 + ra0) * 64 + l7 * 8;
    const int aoff1 = (oc0 + ra1) * 64 + l7 * 8;
    const int adst0 = (wv * 2) * 1024, adst1 = adst0 + 1024;
    size_t bbase[4]; int bdst[4];
    const size_t xsb = (size_t)b * (34 * 34 * 512);
    #pragma unroll
    for (int i = 0; i < 4; ++i) {
        const int p = wv * 32 + i * 8 + lsub;          // pixel row 0..255
        const int n = n0 + p;
        bbase[i] = xsb + ((size_t)(n >> 5) * 34 + (n & 31)) * 512 + sx * 8;
        bdst[i] = 16384 + (wv * 4 + i) * 1024;
    }

#define STAGE_ALL(tt, bo) do { \
        const unsigned short* wsrc_ = wbf + (size_t)(tt) * 32768; \
        const int sh_ = shift_of(tt); \
        gload_lds16(wsrc_ + aoff0, lds + (bo) + adst0); \
        gload_lds16(wsrc_ + aoff1, lds + (bo) + adst1); \
        gload_lds16(xs + bbase[0] + sh_, lds + (bo) + bdst[0]); \
        gload_lds16(xs + bbase[1] + sh_, lds + (bo) + bdst[1]); \
        gload_lds16(xs + bbase[2] + sh_, lds + (bo) + bdst[2]); \
        gload_lds16(xs + bbase[3] + sh_, lds + (bo) + bdst[3]); } while (0)

#define READS(S, cb) do { \
        _Pragma("unroll") \
        for (int mi_ = 0; mi_ < 4; ++mi_) a0##S[mi_] = LDS_RD((cb) + arow + mi_ * 2048 + swz0); \
        _Pragma("unroll") \
        for (int ni_ = 0; ni_ < 4; ++ni_) b0##S[ni_] = LDS_RD((cb) + brow + ni_ * 2048 + swz0); \
        _Pragma("unroll") \
        for (int mi_ = 0; mi_ < 4; ++mi_) a1##S[mi_] = LDS_RD((cb) + arow + mi_ * 2048 + swz1); \
        _Pragma("unroll") \
        for (int ni_ = 0; ni_ < 4; ++ni_) b1##S[ni_] = LDS_RD((cb) + brow + ni_ * 2048 + swz1); } while (0)

#define BARRIER() __builtin_amdgcn_s_barrier()

    f32x4 acc[4][4];
    #pragma unroll
    for (int i = 0; i < 4; ++i)
        #pragma unroll
        for (int j = 0; j < 4; ++j) acc[i][j] = (f32x4){0.f, 0.f, 0.f, 0.f};

    bfx8 a0A[4], a1A[4], b0A[4], b1A[4];
    bfx8 a0B[4], a1B[4], b0B[4], b1B[4];

    // prologue: stage tiles 0,1; wait tile 0; read tile 0 fragments into set A
    STAGE_ALL(0, 0);
    STAGE_ALL(1, 49152);
    asm volatile("s_waitcnt vmcnt(6)" ::: "memory");   // tile 0 landed
    BARRIER();
    READS(A, 0);

    int co = 0;

#define ITER(T, C, N) do { \
        const int t_ = (T); \
        int cn_ = co + 49152; if (cn_ >= 147456) cn_ -= 147456;   /* buf t+1 */ \
        int so_ = co + 98304; if (so_ >= 147456) so_ -= 147456;   /* buf t+2 */ \
        asm volatile("s_waitcnt vmcnt(0)" ::: "memory");          /* S(t+1) landed */ \
        BARRIER(); \
        if (t_ < 70) STAGE_ALL(t_ + 2, so_); \
        if (t_ < 71) READS(N, cn_); \
        __builtin_amdgcn_sched_barrier(0);   /* pin: reads(t+1) issue BEFORE MFMAs(t) */ \
        __builtin_amdgcn_s_setprio(1); \
        _Pragma("unroll") \
        for (int ni_ = 0; ni_ < 4; ++ni_) \
            _Pragma("unroll") \
            for (int mi_ = 0; mi_ < 4; ++mi_) \
                acc[mi_][ni_] = MFMA(a0##C[mi_], b0##C[ni_], acc[mi_][ni_]); \
        _Pragma("unroll") \
        for (int ni_ = 0; ni_ < 4; ++ni_) \
            _Pragma("unroll") \
            for (int mi_ = 0; mi_ < 4; ++mi_) \
                acc[mi_][ni_] = MFMA(a1##C[mi_], b1##C[ni_], acc[mi_][ni_]); \
        __builtin_amdgcn_s_setprio(0); \
        co = cn_; \
    } while (0)

    #pragma unroll 1
    for (int tt = 0; tt < 36; ++tt) {
        ITER(2 * tt,     A, B);
        ITER(2 * tt + 1, B, A);
    }

    // epilogue: scale by demod d[b][oc], write fp32 NCHW
    const int r4 = (lane >> 4) * 4;
    #pragma unroll
    for (int mi = 0; mi < 4; ++mi) {
        #pragma unroll
        for (int rr = 0; rr < 4; ++rr) {
            const int ocr = oc0 + wr * 64 + mi * 16 + r4 + rr;
            const float dv = dcoef[b * 512 + ocr];
            float* orow = out + ((size_t)b * 512 + ocr) * 1024 + n0 + wc * 64 + l15;
            #pragma unroll
            for (int ni = 0; ni < 4; ++ni)
                orow[ni * 16] = acc[mi][ni][rr] * dv;
        }
    }
}

// ---------- launch ----------
extern "C" void kernel_launch(void* const* d_in, const int* in_sizes, int n_in,
                              void* d_out, int out_size, void* d_ws, size_t ws_size,
                              hipStream_t stream) {
    const float* x        = (const float*)d_in[0];   // (16,512,32,32)
    const float* w        = (const float*)d_in[1];   // (16,512)
    const float* weight   = (const float*)d_in[2];   // (512,512,3,3)
    const float* affine_w = (const float*)d_in[3];   // (512,512)
    const float* affine_b = (const float*)d_in[4];   // (512,)
    float* out = (float*)d_out;

    char* ws = (char*)d_ws;
    float*          style = (float*)(ws + 0);                 // 32 KB
    float*          W2    = (float*)(ws + 0x8000);            // 1 MB
    float*          dcoef = (float*)(ws + 0x108000);          // 32 KB
    unsigned short* wbf   = (unsigned short*)(ws + 0x110000); // 4.5 MB
    unsigned short* xs    = (unsigned short*)(ws + 0x590000); // 18.1 MB

    style_kernel<<<2048, 256, 0, stream>>>(w, affine_w, affine_b, style);
    w2wbf_kernel<<<1024, 256, 0, stream>>>(weight, W2, wbf);
    d_kernel<<<2048, 256, 0, stream>>>(style, W2, dcoef);
    border_kernel<<<1056, 256, 0, stream>>>(xs);
    xspad_kernel<<<dim3(4, 32, 16), 256, 0, stream>>>(x, style, xs);
    conv_kernel<<<256, 512, 0, stream>>>(wbf, xs, dcoef, out);
}